// Round 12
// baseline (56.275 us; speedup 1.0000x reference)
//
#include <hip/hip_runtime.h>

// RBF: out[n,m] = exp(-0.5 * max(||A_n||^2 + ||B_m||^2 - 2 A_n.B_m, 0))
// N=M=8192, D=64, fp32 in/out.
// fp16 32x32x16 MFMA cross-term, exact fp32 norms, exp2 epilogue.
// Round 12 = round 11 with compile fix (nt store needs clang ext_vector, not
// HIP float4). LDS-bounce epilogue -> fill-identical store pattern:
// nt dwordx4, 2 rows x 512 B contiguous per instruction. C-tile staged in
// LDS reusing dead Ash/Bsh space (two 32 KB passes); LDS 33 KB, 3 blocks/CU.
// 128x128 tile / 256 threads (4 waves, 2x2 of 64x64), XOR-swizzled LDS.

constexpr int Mdim = 8192;
constexpr int D    = 64;
constexpr int BM   = 128;
constexpr int BN   = 128;
constexpr float NEG_HALF_L2E = -0.72134752044448170f; // -0.5*log2(e)
constexpr float L2E          =  1.44269504088896340f; //  log2(e)

typedef __attribute__((ext_vector_type(8)))  _Float16 f16x8;
typedef __attribute__((ext_vector_type(4)))  float    f32x4;
typedef __attribute__((ext_vector_type(16))) float    f32x16;

__global__ __launch_bounds__(256, 3) void rbf_mfma_58720792871618(
    const float* __restrict__ A, const float* __restrict__ B, float* __restrict__ C)
{
    // Overlaid LDS: stage/MFMA phase uses Ash(16K)+Bsh(16K); epilogue reuses
    // the same 32 KB as a 64-row x 128-col fp32 C-slab per pass.
    __shared__ __align__(16) char sbuf[32768];
    __shared__ float pA[BM];           // -0.5*log2e * ||row||^2
    __shared__ float pB[BN];

    const int tid  = threadIdx.x;
    const int lane = tid & 63;
    const int wid  = tid >> 6;
    const int row0 = blockIdx.y * BM;
    const int col0 = blockIdx.x * BN;

    // ---------------- stage: fp32 -> fp16 into swizzled LDS + fp32 norms ----------------
    {
        const int r  = tid >> 1;           // tile row 0..127 (A and B)
        const int c0 = (tid & 1) * 32;     // column half
        const float4* ga = reinterpret_cast<const float4*>(A + (size_t)(row0 + r) * D + c0);
        const float4* gb = reinterpret_cast<const float4*>(B + (size_t)(col0 + r) * D + c0);

        float sa = 0.f, sb = 0.f;
        f16x8 ha[4], hb[4];
        #pragma unroll
        for (int k = 0; k < 8; ++k) {
            const float4 v = ga[k];
            sa = fmaf(v.x, v.x, fmaf(v.y, v.y, fmaf(v.z, v.z, fmaf(v.w, v.w, sa))));
            const int t = k >> 1, o = (k & 1) * 4;
            ha[t][o + 0] = (_Float16)v.x; ha[t][o + 1] = (_Float16)v.y;
            ha[t][o + 2] = (_Float16)v.z; ha[t][o + 3] = (_Float16)v.w;
        }
        #pragma unroll
        for (int k = 0; k < 8; ++k) {
            const float4 v = gb[k];
            sb = fmaf(v.x, v.x, fmaf(v.y, v.y, fmaf(v.z, v.z, fmaf(v.w, v.w, sb))));
            const int t = k >> 1, o = (k & 1) * 4;
            hb[t][o + 0] = (_Float16)v.x; hb[t][o + 1] = (_Float16)v.y;
            hb[t][o + 2] = (_Float16)v.z; hb[t][o + 3] = (_Float16)v.w;
        }

        char* abase = sbuf + r * 128;
        char* bbase = sbuf + 16384 + r * 128;
        #pragma unroll
        for (int t = 0; t < 4; ++t) {
            const int sw = (c0 * 2 + t * 16) ^ ((r & 7) << 4);
            *reinterpret_cast<f16x8*>(abase + sw) = ha[t];
        }
        #pragma unroll
        for (int t = 0; t < 4; ++t) {
            const int sw = (c0 * 2 + t * 16) ^ ((r & 7) << 4);
            *reinterpret_cast<f16x8*>(bbase + sw) = hb[t];
        }

        sa += __shfl_xor(sa, 1);
        sb += __shfl_xor(sb, 1);
        if ((tid & 1) == 0) { pA[r] = NEG_HALF_L2E * sa; pB[r] = NEG_HALF_L2E * sb; }
    }
    __syncthreads();

    // ---------------- MFMA: 64x64 per wave, 2x2 fragments of 32x32, K=64 ----------------
    // C/D: col = lane&31, row = (reg&3) + 8*(reg>>2) + 4*(lane>>5)
    const int wr  = (wid >> 1) * 64;   // wave row base in tile
    const int wc  = (wid & 1) * 64;    // wave col base in tile
    const int l31 = lane & 31;
    const int hi  = lane >> 5;

    const int arow0 = wr + l31,  arow1 = wr + 32 + l31;
    const int brow0 = wc + l31,  brow1 = wc + 32 + l31;
    const char* ab = sbuf;
    const char* bb = sbuf + 16384;

    f32x16 acc[2][2] = {};

    #pragma unroll
    for (int ks = 0; ks < 4; ++ks) {
        const int kb = ks * 32 + hi * 16;   // byte offset of this lane's k-slice
        f16x8 af[2], bf[2];
        af[0] = *reinterpret_cast<const f16x8*>(ab + arow0 * 128 + (kb ^ ((arow0 & 7) << 4)));
        af[1] = *reinterpret_cast<const f16x8*>(ab + arow1 * 128 + (kb ^ ((arow1 & 7) << 4)));
        bf[0] = *reinterpret_cast<const f16x8*>(bb + brow0 * 128 + (kb ^ ((brow0 & 7) << 4)));
        bf[1] = *reinterpret_cast<const f16x8*>(bb + brow1 * 128 + (kb ^ ((brow1 & 7) << 4)));
        #pragma unroll
        for (int mf = 0; mf < 2; ++mf)
            #pragma unroll
            for (int nf = 0; nf < 2; ++nf)
                acc[mf][nf] = __builtin_amdgcn_mfma_f32_32x32x16_f16(
                    af[mf], bf[nf], acc[mf][nf], 0, 0, 0);
    }
    __syncthreads();   // frags fully consumed -> safe to overwrite sbuf with C values

    // ---------------- epilogue: 2 passes, each 64 rows x 128 cols via LDS ----------------
    // Pass p covers tile rows {wr + p*32 .. wr+p*32+31} for each wave pair.
    // LDS slot s = (wid>>1)*32 + rowoff  maps to tile row (s>>5)*64 + p*32 + (s&31).
    float* Cbuf = reinterpret_cast<float*>(sbuf);
    const float pb0 = pB[wc + l31];
    const float pb1 = pB[wc + 32 + l31];

    #pragma unroll
    for (int p = 0; p < 2; ++p) {
        // compute exp values and scatter into LDS slab (bank-clean: stride-1 cols)
        #pragma unroll
        for (int g = 0; g < 4; ++g) {
            #pragma unroll
            for (int q = 0; q < 4; ++q) {
                const int ro = 4 * hi + 8 * g + q;        // 0..31
                const int rt = wr + p * 32 + ro;          // row in tile
                const int s  = (wid >> 1) * 32 + ro;      // LDS slot 0..63
                const float pav = pA[rt];
                const int e = g * 4 + q;
                const float t0 = fmaf(L2E, acc[p][0][e], pav + pb0);
                const float t1 = fmaf(L2E, acc[p][1][e], pav + pb1);
                Cbuf[s * 128 + wc + l31]      = __builtin_amdgcn_exp2f(fminf(t0, 0.0f));
                Cbuf[s * 128 + wc + 32 + l31] = __builtin_amdgcn_exp2f(fminf(t1, 0.0f));
            }
        }
        __syncthreads();

        // sweep: fill-style nt dwordx4 stores, 2 rows x 512 B contiguous per instr
        #pragma unroll
        for (int i = 0; i < 8; ++i) {
            const int srow = wid * 16 + i * 2 + hi;       // LDS slot 0..63
            const f32x4 v = *reinterpret_cast<const f32x4*>(&Cbuf[srow * 128 + l31 * 4]);
            const int grow = row0 + (srow >> 5) * 64 + p * 32 + (srow & 31);
            __builtin_nontemporal_store(
                v, reinterpret_cast<f32x4*>(C + (size_t)grow * Mdim + col0 + l31 * 4));
        }
        __syncthreads();
    }
}

extern "C" void kernel_launch(void* const* d_in, const int* /*in_sizes*/, int /*n_in*/,
                              void* d_out, int /*out_size*/, void* /*d_ws*/, size_t /*ws_size*/,
                              hipStream_t stream)
{
    const float* A = (const float*)d_in[0];   // input_1 [8192, 64]
    const float* B = (const float*)d_in[1];   // input_2 [8192, 64]
    float* C = (float*)d_out;                 // [8192, 8192]
    dim3 grid(Mdim / BN, 8192 / BM);
    rbf_mfma_58720792871618<<<grid, 256, 0, stream>>>(A, B, C);
}

// Round 13
// 54.921 us; speedup vs baseline: 1.0247x; 1.0247x over previous
//
#include <hip/hip_runtime.h>

// RBF: out[n,m] = exp(-0.5 * max(||A_n||^2 + ||B_m||^2 - 2 A_n.B_m, 0))
// N=M=8192, D=64, fp32 in/out.
// FINAL (= round-5 best, 53.6us): fp16 32x32x16 MFMA cross-term, exact fp32
// norms, exp2 epilogue, nontemporal scalar stores (2 rows x 128 B/instr).
// Measured at the tiled-write DRAM ceiling (~5.0 TB/s effective; 8 write-side
// variants within 53.6-57us). 128x128 tile / 256 threads (4 waves, 2x2 of
// 64x64), XOR-swizzled LDS, 3 blocks/CU.

constexpr int Mdim = 8192;
constexpr int D    = 64;
constexpr int BM   = 128;
constexpr int BN   = 128;
constexpr float NEG_HALF_L2E = -0.72134752044448170f; // -0.5*log2(e)
constexpr float L2E          =  1.44269504088896340f; //  log2(e)

typedef __attribute__((ext_vector_type(8)))  _Float16 f16x8;
typedef __attribute__((ext_vector_type(16))) float    f32x16;

__global__ __launch_bounds__(256, 3) void rbf_mfma_58720792871618(
    const float* __restrict__ A, const float* __restrict__ B, float* __restrict__ C)
{
    __shared__ _Float16 Ash[BM * D];   // row-major, 128 B/row, XOR-swizzled 16B slots
    __shared__ _Float16 Bsh[BN * D];
    __shared__ float pA[BM];           // -0.5*log2e * ||row||^2
    __shared__ float pB[BN];

    const int tid  = threadIdx.x;
    const int lane = tid & 63;
    const int wid  = tid >> 6;
    const int row0 = blockIdx.y * BM;
    const int col0 = blockIdx.x * BN;

    // ---------------- stage: fp32 -> fp16 into swizzled LDS + fp32 norms ----------------
    {
        const int r  = tid >> 1;           // tile row 0..127 (A and B)
        const int c0 = (tid & 1) * 32;     // column half
        const float4* ga = reinterpret_cast<const float4*>(A + (size_t)(row0 + r) * D + c0);
        const float4* gb = reinterpret_cast<const float4*>(B + (size_t)(col0 + r) * D + c0);

        float sa = 0.f, sb = 0.f;
        f16x8 ha[4], hb[4];
        #pragma unroll
        for (int k = 0; k < 8; ++k) {
            const float4 v = ga[k];
            sa = fmaf(v.x, v.x, fmaf(v.y, v.y, fmaf(v.z, v.z, fmaf(v.w, v.w, sa))));
            const int t = k >> 1, o = (k & 1) * 4;
            ha[t][o + 0] = (_Float16)v.x; ha[t][o + 1] = (_Float16)v.y;
            ha[t][o + 2] = (_Float16)v.z; ha[t][o + 3] = (_Float16)v.w;
        }
        #pragma unroll
        for (int k = 0; k < 8; ++k) {
            const float4 v = gb[k];
            sb = fmaf(v.x, v.x, fmaf(v.y, v.y, fmaf(v.z, v.z, fmaf(v.w, v.w, sb))));
            const int t = k >> 1, o = (k & 1) * 4;
            hb[t][o + 0] = (_Float16)v.x; hb[t][o + 1] = (_Float16)v.y;
            hb[t][o + 2] = (_Float16)v.z; hb[t][o + 3] = (_Float16)v.w;
        }

        char* abase = reinterpret_cast<char*>(Ash) + r * 128;
        char* bbase = reinterpret_cast<char*>(Bsh) + r * 128;
        #pragma unroll
        for (int t = 0; t < 4; ++t) {
            const int sw = (c0 * 2 + t * 16) ^ ((r & 7) << 4);
            *reinterpret_cast<f16x8*>(abase + sw) = ha[t];
        }
        #pragma unroll
        for (int t = 0; t < 4; ++t) {
            const int sw = (c0 * 2 + t * 16) ^ ((r & 7) << 4);
            *reinterpret_cast<f16x8*>(bbase + sw) = hb[t];
        }

        sa += __shfl_xor(sa, 1);
        sb += __shfl_xor(sb, 1);
        if ((tid & 1) == 0) { pA[r] = NEG_HALF_L2E * sa; pB[r] = NEG_HALF_L2E * sb; }
    }
    __syncthreads();

    // ---------------- MFMA: 64x64 per wave, 2x2 fragments of 32x32, K=64 ----------------
    // C/D: col = lane&31, row = (reg&3) + 8*(reg>>2) + 4*(lane>>5)
    const int wr  = (wid >> 1) * 64;   // wave row base in tile
    const int wc  = (wid & 1) * 64;    // wave col base in tile
    const int l31 = lane & 31;
    const int hi  = lane >> 5;

    const int arow0 = wr + l31,  arow1 = wr + 32 + l31;
    const int brow0 = wc + l31,  brow1 = wc + 32 + l31;
    const char* ab = reinterpret_cast<const char*>(Ash);
    const char* bb = reinterpret_cast<const char*>(Bsh);

    f32x16 acc[2][2] = {};

    #pragma unroll
    for (int ks = 0; ks < 4; ++ks) {
        const int kb = ks * 32 + hi * 16;   // byte offset of this lane's k-slice
        f16x8 af[2], bf[2];
        af[0] = *reinterpret_cast<const f16x8*>(ab + arow0 * 128 + (kb ^ ((arow0 & 7) << 4)));
        af[1] = *reinterpret_cast<const f16x8*>(ab + arow1 * 128 + (kb ^ ((arow1 & 7) << 4)));
        bf[0] = *reinterpret_cast<const f16x8*>(bb + brow0 * 128 + (kb ^ ((brow0 & 7) << 4)));
        bf[1] = *reinterpret_cast<const f16x8*>(bb + brow1 * 128 + (kb ^ ((brow1 & 7) << 4)));
        #pragma unroll
        for (int mf = 0; mf < 2; ++mf)
            #pragma unroll
            for (int nf = 0; nf < 2; ++nf)
                acc[mf][nf] = __builtin_amdgcn_mfma_f32_32x32x16_f16(
                    af[mf], bf[nf], acc[mf][nf], 0, 0, 0);
    }

    // ---------------- epilogue: t = log2e*acc + pa + pb; out = exp2(min(t,0)) ----------------
    // Nontemporal scalar-dword stores: 2 rows x 128 B contiguous per instruction.
    const float pb0 = pB[wc + l31];
    const float pb1 = pB[wc + 32 + l31];

    #pragma unroll
    for (int mf = 0; mf < 2; ++mf) {
        #pragma unroll
        for (int g = 0; g < 4; ++g) {
            #pragma unroll
            for (int q = 0; q < 4; ++q) {
                const int rt = wr + mf * 32 + 4 * hi + 8 * g + q;   // row in tile
                const float pav = pA[rt];
                float* crow = C + (size_t)(row0 + rt) * Mdim + (col0 + wc + l31);
                const int e = g * 4 + q;
                float t0 = fmaf(L2E, acc[mf][0][e], pav + pb0);
                float t1 = fmaf(L2E, acc[mf][1][e], pav + pb1);
                __builtin_nontemporal_store(
                    __builtin_amdgcn_exp2f(fminf(t0, 0.0f)), crow + 0);
                __builtin_nontemporal_store(
                    __builtin_amdgcn_exp2f(fminf(t1, 0.0f)), crow + 32);
            }
        }
    }
}

extern "C" void kernel_launch(void* const* d_in, const int* /*in_sizes*/, int /*n_in*/,
                              void* d_out, int /*out_size*/, void* /*d_ws*/, size_t /*ws_size*/,
                              hipStream_t stream)
{
    const float* A = (const float*)d_in[0];   // input_1 [8192, 64]
    const float* B = (const float*)d_in[1];   // input_2 [8192, 64]
    float* C = (float*)d_out;                 // [8192, 8192]
    dim3 grid(Mdim / BN, 8192 / BM);
    rbf_mfma_58720792871618<<<grid, 256, 0, stream>>>(A, B, C);
}